// Round 4
// baseline (872.213 us; speedup 1.0000x reference)
//
#include <hip/hip_runtime.h>

#define N_NODES 100000
#define N_EDGES 3200000
#define EMB 128
#define N_GRAPH 1024
#define N_CLASS 10

#define SCAN_B 1024
#define NB_SCAN ((N_NODES + SCAN_B - 1) / SCAN_B)  // 98

typedef unsigned int uint32;
typedef __attribute__((ext_vector_type(8))) short bf16x8;
typedef __attribute__((ext_vector_type(4))) float f32x4;

__device__ inline unsigned short f2bf(float f) {
  unsigned u = __float_as_uint(f);
  u += 0x7fffu + ((u >> 16) & 1u);
  return (unsigned short)(u >> 16);
}
__device__ inline float bf2f(unsigned short s) {
  return __uint_as_float(((unsigned)s) << 16);
}

// ---------------- embedding: x = shape_emb[s] + color_emb[c] + pos_emb[p] ----
__global__ void k_embed(const int* __restrict__ nf, const float* __restrict__ se,
                        const float* __restrict__ ce, const float* __restrict__ pe,
                        unsigned short* __restrict__ X) {
  int gid = blockIdx.x * blockDim.x + threadIdx.x;  // N_NODES*16 threads, 8 elems each
  if (gid >= N_NODES * 16) return;
  int node = gid >> 4;
  int q = (gid & 15) * 8;
  int s = nf[node * 3 + 0];
  int c = nf[node * 3 + 1];
  int p = nf[node * 3 + 2];
  const float* ps = se + s * EMB + q;
  const float* pc = ce + c * EMB + q;
  const float* pp = pe + p * EMB + q;
  float4 a0 = *(const float4*)ps, a1 = *(const float4*)(ps + 4);
  float4 b0 = *(const float4*)pc, b1 = *(const float4*)(pc + 4);
  float4 d0 = *(const float4*)pp, d1 = *(const float4*)(pp + 4);
  float r0 = a0.x + b0.x + d0.x, r1 = a0.y + b0.y + d0.y;
  float r2 = a0.z + b0.z + d0.z, r3 = a0.w + b0.w + d0.w;
  float r4 = a1.x + b1.x + d1.x, r5 = a1.y + b1.y + d1.y;
  float r6 = a1.z + b1.z + d1.z, r7 = a1.w + b1.w + d1.w;
  uint4 o;
  o.x = (uint32)f2bf(r0) | ((uint32)f2bf(r1) << 16);
  o.y = (uint32)f2bf(r2) | ((uint32)f2bf(r3) << 16);
  o.z = (uint32)f2bf(r4) | ((uint32)f2bf(r5) << 16);
  o.w = (uint32)f2bf(r6) | ((uint32)f2bf(r7) << 16);
  *(uint4*)(X + (size_t)node * EMB + q) = o;
}

// ---------------- degree count, 4 edges/thread -------------------------------
__global__ __launch_bounds__(256) void k_count(const int* __restrict__ dst,
                                               int* __restrict__ degi) {
  const int T = N_EDGES / 4;
  int t = blockIdx.x * blockDim.x + threadIdx.x;
  if (t >= T) return;
  int d0 = dst[t];
  int d1 = dst[t + T];
  int d2 = dst[t + 2 * T];
  int d3 = dst[t + 3 * T];
  atomicAdd(&degi[d0], 1);
  atomicAdd(&degi[d1], 1);
  atomicAdd(&degi[d2], 1);
  atomicAdd(&degi[d3], 1);
}

// ---------------- block-wise exclusive scan ---------------------------------
__global__ void k_scan1(const int* __restrict__ degi, int* __restrict__ offs,
                        int* __restrict__ part) {
  __shared__ int t[SCAN_B];
  int tid = threadIdx.x;
  int gid = blockIdx.x * SCAN_B + tid;
  int v = (gid < N_NODES) ? degi[gid] : 0;
  t[tid] = v;
  __syncthreads();
  for (int s = 1; s < SCAN_B; s <<= 1) {
    int u = (tid >= s) ? t[tid - s] : 0;
    __syncthreads();
    t[tid] += u;
    __syncthreads();
  }
  if (gid < N_NODES) offs[gid] = t[tid] - v;
  if (tid == SCAN_B - 1) part[blockIdx.x] = t[tid];
}

__global__ void k_scan2(int* __restrict__ part) {
  __shared__ int t[128];
  int tid = threadIdx.x;
  int v = (tid < NB_SCAN) ? part[tid] : 0;
  t[tid] = v;
  __syncthreads();
  for (int s = 1; s < 128; s <<= 1) {
    int u = (tid >= s) ? t[tid - s] : 0;
    __syncthreads();
    t[tid] += u;
    __syncthreads();
  }
  if (tid < NB_SCAN) part[tid] = t[tid] - v;
}

__global__ void k_fin(int* __restrict__ offs, const int* __restrict__ part,
                      const int* __restrict__ degi, int* __restrict__ cursor,
                      float* __restrict__ deginv) {
  int gid = blockIdx.x * blockDim.x + threadIdx.x;
  if (gid >= N_NODES) return;
  int o = offs[gid] + part[gid >> 10];
  offs[gid] = o;
  cursor[gid] = o;
  int d = degi[gid];
  deginv[gid] = d > 0 ? 1.0f / (float)d : 0.0f;
}

// ---------------- CSR fill, 4 edges/thread -----------------------------------
__global__ __launch_bounds__(256) void k_fill(const int* __restrict__ src,
                                              const int* __restrict__ dst,
                                              int* __restrict__ cursor,
                                              int* __restrict__ csr) {
  const int T = N_EDGES / 4;
  int t = blockIdx.x * blockDim.x + threadIdx.x;
  if (t >= T) return;
  int d0 = dst[t];
  int d1 = dst[t + T];
  int d2 = dst[t + 2 * T];
  int d3 = dst[t + 3 * T];
  int s0 = src[t];
  int s1 = src[t + T];
  int s2 = src[t + 2 * T];
  int s3 = src[t + 3 * T];
  int p0 = atomicAdd(&cursor[d0], 1);
  int p1 = atomicAdd(&cursor[d1], 1);
  int p2 = atomicAdd(&cursor[d2], 1);
  int p3 = atomicAdd(&cursor[d3], 1);
  csr[p0] = s0;
  csr[p1] = s1;
  csr[p2] = s2;
  csr[p3] = s3;
}

// ---------------- build concatenated bf16 weights: Wcat[j][k], k 0..255 ------
__global__ void k_wcat(const float* __restrict__ wl, const float* __restrict__ wr,
                       unsigned short* __restrict__ wcat) {
  int gid = blockIdx.x * blockDim.x + threadIdx.x;  // 128*256 = 32768
  int j = gid >> 8;
  int k = gid & 255;
  float v = (k < EMB) ? wl[j * EMB + k] : wr[j * EMB + (k - EMB)];
  wcat[gid] = f2bf(v);
}

// ---------------- mean aggregation over incoming edges (CSR, bf16) -----------
__global__ __launch_bounds__(256) void k_agg(const unsigned short* __restrict__ in,
                                             unsigned short* __restrict__ out,
                                             const int* __restrict__ offs,
                                             const int* __restrict__ degi,
                                             const float* __restrict__ deginv,
                                             const int* __restrict__ csr) {
  int wave = threadIdx.x >> 6;
  int lane = threadIdx.x & 63;
  int node = blockIdx.x * 4 + wave;
  int start = offs[node];
  int cnt = degi[node];
  int lo = lane * 2;
  float ax = 0.f, ay = 0.f;
  int i = 0;
  for (; i + 8 <= cnt; i += 8) {
    int s0 = csr[start + i + 0];
    int s1 = csr[start + i + 1];
    int s2 = csr[start + i + 2];
    int s3 = csr[start + i + 3];
    int s4 = csr[start + i + 4];
    int s5 = csr[start + i + 5];
    int s6 = csr[start + i + 6];
    int s7 = csr[start + i + 7];
    uint32 v0 = *(const uint32*)(in + (size_t)s0 * EMB + lo);
    uint32 v1 = *(const uint32*)(in + (size_t)s1 * EMB + lo);
    uint32 v2 = *(const uint32*)(in + (size_t)s2 * EMB + lo);
    uint32 v3 = *(const uint32*)(in + (size_t)s3 * EMB + lo);
    uint32 v4 = *(const uint32*)(in + (size_t)s4 * EMB + lo);
    uint32 v5 = *(const uint32*)(in + (size_t)s5 * EMB + lo);
    uint32 v6 = *(const uint32*)(in + (size_t)s6 * EMB + lo);
    uint32 v7 = *(const uint32*)(in + (size_t)s7 * EMB + lo);
    ax += __uint_as_float(v0 << 16) + __uint_as_float(v1 << 16) +
          __uint_as_float(v2 << 16) + __uint_as_float(v3 << 16) +
          __uint_as_float(v4 << 16) + __uint_as_float(v5 << 16) +
          __uint_as_float(v6 << 16) + __uint_as_float(v7 << 16);
    ay += __uint_as_float(v0 & 0xffff0000u) + __uint_as_float(v1 & 0xffff0000u) +
          __uint_as_float(v2 & 0xffff0000u) + __uint_as_float(v3 & 0xffff0000u) +
          __uint_as_float(v4 & 0xffff0000u) + __uint_as_float(v5 & 0xffff0000u) +
          __uint_as_float(v6 & 0xffff0000u) + __uint_as_float(v7 & 0xffff0000u);
  }
  for (; i < cnt; ++i) {
    int s = csr[start + i];
    uint32 v = *(const uint32*)(in + (size_t)s * EMB + lo);
    ax += __uint_as_float(v << 16);
    ay += __uint_as_float(v & 0xffff0000u);
  }
  float di = deginv[node];
  uint32 packed = (uint32)f2bf(ax * di) | ((uint32)f2bf(ay * di) << 16);
  *(uint32*)(out + (size_t)node * EMB + lo) = packed;
}

// ---------------- fused MFMA GEMM: out = relu([A|S] @ WcatT + bias), bf16 ----
__global__ __launch_bounds__(256) void k_gemm(const unsigned short* __restrict__ A,
                                              const unsigned short* __restrict__ S,
                                              const unsigned short* __restrict__ Wcat,
                                              const float* __restrict__ bias,
                                              unsigned short* __restrict__ out) {
  int wid = threadIdx.x >> 6;
  int lane = threadIdx.x & 63;
  int rows0 = blockIdx.x * 64 + wid * 16;
  int r = lane & 15;
  int khalf = lane >> 4;
  int arow = rows0 + r;
  if (arow > N_NODES - 1) arow = N_NODES - 1;
  const unsigned short* Abase = A + (size_t)arow * EMB + khalf * 8;
  const unsigned short* Sbase = S + (size_t)arow * EMB + khalf * 8;

  f32x4 acc[8] = {};
#pragma unroll
  for (int kc = 0; kc < 8; ++kc) {
    const unsigned short* p = (kc < 4) ? (Abase + kc * 32) : (Sbase + (kc - 4) * 32);
    bf16x8 a = *(const bf16x8*)p;
#pragma unroll
    for (int jc = 0; jc < 8; ++jc) {
      bf16x8 b = *(const bf16x8*)(Wcat + (size_t)(jc * 16 + r) * 256 + kc * 32 + khalf * 8);
      acc[jc] = __builtin_amdgcn_mfma_f32_16x16x32_bf16(a, b, acc[jc], 0, 0, 0);
    }
  }

  int rbase = (lane >> 4) * 4;
#pragma unroll
  for (int jc = 0; jc < 8; ++jc) {
    int col = jc * 16 + r;
    float bv = bias[col];
#pragma unroll
    for (int q = 0; q < 4; ++q) {
      int row = rows0 + rbase + q;
      if (row < N_NODES) {
        float v = fmaxf(acc[jc][q] + bv, 0.f);
        out[(size_t)row * EMB + col] = f2bf(v);
      }
    }
  }
}

// ---------------- mean pooling per graph + linear head -----------------------
__global__ void k_pool(const unsigned short* __restrict__ h, const int* __restrict__ batch,
                       const float* __restrict__ lw, const float* __restrict__ lb,
                       float* __restrict__ out) {
  int g = blockIdx.x;
  int tid = threadIdx.x;  // 128
  int lo = 0, hi = N_NODES;
  while (lo < hi) {
    int mid = (lo + hi) >> 1;
    if (batch[mid] < g) lo = mid + 1; else hi = mid;
  }
  int lo2 = lo, hi2 = N_NODES;
  while (lo2 < hi2) {
    int mid = (lo2 + hi2) >> 1;
    if (batch[mid] < g + 1) lo2 = mid + 1; else hi2 = mid;
  }
  float sum = 0.f;
  for (int n = lo; n < lo2; ++n) sum += bf2f(h[(size_t)n * EMB + tid]);
  int cnt = lo2 - lo;
  float pooled = sum / fmaxf((float)cnt, 1.0f);
  __shared__ float pl[EMB];
  pl[tid] = pooled;
  __syncthreads();
  if (tid < N_CLASS) {
    float o = lb[tid];
    for (int d = 0; d < EMB; ++d) o += pl[d] * lw[tid * EMB + d];
    out[g * N_CLASS + tid] = o;
  }
}

extern "C" void kernel_launch(void* const* d_in, const int* in_sizes, int n_in,
                              void* d_out, int out_size, void* d_ws, size_t ws_size,
                              hipStream_t stream) {
  const int* nf = (const int*)d_in[0];
  const int* ei = (const int*)d_in[1];
  const int* batch = (const int*)d_in[2];
  const float* se = (const float*)d_in[3];
  const float* ce = (const float*)d_in[4];
  const float* pe = (const float*)d_in[5];
  const float* w1l = (const float*)d_in[6];
  const float* b1l = (const float*)d_in[7];
  const float* w1r = (const float*)d_in[8];
  const float* w2l = (const float*)d_in[9];
  const float* b2l = (const float*)d_in[10];
  const float* w2r = (const float*)d_in[11];
  const float* linw = (const float*)d_in[12];
  const float* linb = (const float*)d_in[13];
  float* out = (float*)d_out;

  char* ws = (char*)d_ws;
  size_t off = 0;
  auto alloc = [&](size_t bytes) {
    void* p = ws + off;
    off = (off + bytes + 255) & ~(size_t)255;
    return p;
  };
  unsigned short* X = (unsigned short*)alloc((size_t)N_NODES * EMB * 2);
  unsigned short* H = (unsigned short*)alloc((size_t)N_NODES * EMB * 2);
  unsigned short* AGG = (unsigned short*)alloc((size_t)N_NODES * EMB * 2);
  unsigned short* WC1 = (unsigned short*)alloc((size_t)256 * EMB * 2);
  unsigned short* WC2 = (unsigned short*)alloc((size_t)256 * EMB * 2);
  float* deginv = (float*)alloc((size_t)N_NODES * 4);
  int* degi = (int*)alloc((size_t)N_NODES * 4);
  int* offs = (int*)alloc((size_t)N_NODES * 4);
  int* cursor = (int*)alloc((size_t)N_NODES * 4);
  int* part = (int*)alloc((size_t)128 * 4);
  int* csr = (int*)alloc((size_t)N_EDGES * 4);

  const int* srcv = ei;
  const int* dstv = ei + N_EDGES;

  hipMemsetAsync(degi, 0, (size_t)N_NODES * 4, stream);
  k_embed<<<(N_NODES * 16 + 255) / 256, 256, 0, stream>>>(nf, se, ce, pe, X);
  k_count<<<(N_EDGES / 4 + 255) / 256, 256, 0, stream>>>(dstv, degi);
  k_scan1<<<NB_SCAN, SCAN_B, 0, stream>>>(degi, offs, part);
  k_scan2<<<1, 128, 0, stream>>>(part);
  k_fin<<<(N_NODES + 255) / 256, 256, 0, stream>>>(offs, part, degi, cursor, deginv);
  k_fill<<<(N_EDGES / 4 + 255) / 256, 256, 0, stream>>>(srcv, dstv, cursor, csr);
  k_wcat<<<128, 256, 0, stream>>>(w1l, w1r, WC1);
  k_wcat<<<128, 256, 0, stream>>>(w2l, w2r, WC2);

  k_agg<<<N_NODES / 4, 256, 0, stream>>>(X, AGG, offs, degi, deginv, csr);
  k_gemm<<<(N_NODES + 63) / 64, 256, 0, stream>>>(AGG, X, WC1, b1l, H);
  k_agg<<<N_NODES / 4, 256, 0, stream>>>(H, AGG, offs, degi, deginv, csr);
  k_gemm<<<(N_NODES + 63) / 64, 256, 0, stream>>>(AGG, H, WC2, b2l, X);
  k_pool<<<N_GRAPH, EMB, 0, stream>>>(X, batch, linw, linb, out);
}

// Round 5
// 605.801 us; speedup vs baseline: 1.4398x; 1.4398x over previous
//
#include <hip/hip_runtime.h>

#define N_NODES 100000
#define N_EDGES 3200000
#define EMB 128
#define N_GRAPH 1024
#define N_CLASS 10

#define SCAN_B 1024
#define NB_SCAN ((N_NODES + SCAN_B - 1) / SCAN_B)  // 98

typedef unsigned int uint32;
typedef __attribute__((ext_vector_type(8))) short bf16x8;
typedef __attribute__((ext_vector_type(4))) float f32x4;

__device__ inline unsigned short f2bf(float f) {
  unsigned u = __float_as_uint(f);
  u += 0x7fffu + ((u >> 16) & 1u);
  return (unsigned short)(u >> 16);
}
__device__ inline float bf2f(unsigned short s) {
  return __uint_as_float(((unsigned)s) << 16);
}

// ---------------- embedding: x = shape_emb[s] + color_emb[c] + pos_emb[p] ----
__global__ void k_embed(const int* __restrict__ nf, const float* __restrict__ se,
                        const float* __restrict__ ce, const float* __restrict__ pe,
                        unsigned short* __restrict__ X) {
  int gid = blockIdx.x * blockDim.x + threadIdx.x;  // N_NODES*16 threads, 8 elems each
  if (gid >= N_NODES * 16) return;
  int node = gid >> 4;
  int q = (gid & 15) * 8;
  int s = nf[node * 3 + 0];
  int c = nf[node * 3 + 1];
  int p = nf[node * 3 + 2];
  const float* ps = se + s * EMB + q;
  const float* pc = ce + c * EMB + q;
  const float* pp = pe + p * EMB + q;
  float4 a0 = *(const float4*)ps, a1 = *(const float4*)(ps + 4);
  float4 b0 = *(const float4*)pc, b1 = *(const float4*)(pc + 4);
  float4 d0 = *(const float4*)pp, d1 = *(const float4*)(pp + 4);
  float r0 = a0.x + b0.x + d0.x, r1 = a0.y + b0.y + d0.y;
  float r2 = a0.z + b0.z + d0.z, r3 = a0.w + b0.w + d0.w;
  float r4 = a1.x + b1.x + d1.x, r5 = a1.y + b1.y + d1.y;
  float r6 = a1.z + b1.z + d1.z, r7 = a1.w + b1.w + d1.w;
  uint4 o;
  o.x = (uint32)f2bf(r0) | ((uint32)f2bf(r1) << 16);
  o.y = (uint32)f2bf(r2) | ((uint32)f2bf(r3) << 16);
  o.z = (uint32)f2bf(r4) | ((uint32)f2bf(r5) << 16);
  o.w = (uint32)f2bf(r6) | ((uint32)f2bf(r7) << 16);
  *(uint4*)(X + (size_t)node * EMB + q) = o;
}

// ---------------- count + per-edge rank (ONE atomic per edge total) ----------
__global__ __launch_bounds__(256) void k_rank(const int* __restrict__ dst,
                                              int* __restrict__ degi,
                                              int* __restrict__ rank) {
  int e = blockIdx.x * blockDim.x + threadIdx.x;
  if (e < N_EDGES) rank[e] = atomicAdd(&degi[dst[e]], 1);
}

// ---------------- block-wise exclusive scan ---------------------------------
__global__ void k_scan1(const int* __restrict__ degi, int* __restrict__ offs,
                        int* __restrict__ part) {
  __shared__ int t[SCAN_B];
  int tid = threadIdx.x;
  int gid = blockIdx.x * SCAN_B + tid;
  int v = (gid < N_NODES) ? degi[gid] : 0;
  t[tid] = v;
  __syncthreads();
  for (int s = 1; s < SCAN_B; s <<= 1) {
    int u = (tid >= s) ? t[tid - s] : 0;
    __syncthreads();
    t[tid] += u;
    __syncthreads();
  }
  if (gid < N_NODES) offs[gid] = t[tid] - v;
  if (tid == SCAN_B - 1) part[blockIdx.x] = t[tid];
}

__global__ void k_scan2(int* __restrict__ part) {
  __shared__ int t[128];
  int tid = threadIdx.x;
  int v = (tid < NB_SCAN) ? part[tid] : 0;
  t[tid] = v;
  __syncthreads();
  for (int s = 1; s < 128; s <<= 1) {
    int u = (tid >= s) ? t[tid - s] : 0;
    __syncthreads();
    t[tid] += u;
    __syncthreads();
  }
  if (tid < NB_SCAN) part[tid] = t[tid] - v;
}

__global__ void k_fin(int* __restrict__ offs, const int* __restrict__ part,
                      const int* __restrict__ degi, float* __restrict__ deginv) {
  int gid = blockIdx.x * blockDim.x + threadIdx.x;
  if (gid >= N_NODES) return;
  offs[gid] = offs[gid] + part[gid >> 10];
  int d = degi[gid];
  deginv[gid] = d > 0 ? 1.0f / (float)d : 0.0f;
}

// ---------------- CSR fill, atomic-free --------------------------------------
__global__ __launch_bounds__(256) void k_fill(const int* __restrict__ src,
                                              const int* __restrict__ dst,
                                              const int* __restrict__ offs,
                                              const int* __restrict__ rank,
                                              int* __restrict__ csr) {
  int e = blockIdx.x * blockDim.x + threadIdx.x;
  if (e < N_EDGES) {
    csr[offs[dst[e]] + rank[e]] = src[e];
  }
}

// ---------------- build concatenated bf16 weights: Wcat[j][k], k 0..255 ------
__global__ void k_wcat(const float* __restrict__ wl, const float* __restrict__ wr,
                       unsigned short* __restrict__ wcat) {
  int gid = blockIdx.x * blockDim.x + threadIdx.x;  // 128*256 = 32768
  int j = gid >> 8;
  int k = gid & 255;
  float v = (k < EMB) ? wl[j * EMB + k] : wr[j * EMB + (k - EMB)];
  wcat[gid] = f2bf(v);
}

// ---------------- mean aggregation over incoming edges (CSR, bf16) -----------
__global__ __launch_bounds__(256) void k_agg(const unsigned short* __restrict__ in,
                                             unsigned short* __restrict__ out,
                                             const int* __restrict__ offs,
                                             const int* __restrict__ degi,
                                             const float* __restrict__ deginv,
                                             const int* __restrict__ csr) {
  int wave = threadIdx.x >> 6;
  int lane = threadIdx.x & 63;
  int node = blockIdx.x * 4 + wave;
  int start = offs[node];
  int cnt = degi[node];
  int lo = lane * 2;
  float ax = 0.f, ay = 0.f;
  int i = 0;
  for (; i + 8 <= cnt; i += 8) {
    int s0 = csr[start + i + 0];
    int s1 = csr[start + i + 1];
    int s2 = csr[start + i + 2];
    int s3 = csr[start + i + 3];
    int s4 = csr[start + i + 4];
    int s5 = csr[start + i + 5];
    int s6 = csr[start + i + 6];
    int s7 = csr[start + i + 7];
    uint32 v0 = *(const uint32*)(in + (size_t)s0 * EMB + lo);
    uint32 v1 = *(const uint32*)(in + (size_t)s1 * EMB + lo);
    uint32 v2 = *(const uint32*)(in + (size_t)s2 * EMB + lo);
    uint32 v3 = *(const uint32*)(in + (size_t)s3 * EMB + lo);
    uint32 v4 = *(const uint32*)(in + (size_t)s4 * EMB + lo);
    uint32 v5 = *(const uint32*)(in + (size_t)s5 * EMB + lo);
    uint32 v6 = *(const uint32*)(in + (size_t)s6 * EMB + lo);
    uint32 v7 = *(const uint32*)(in + (size_t)s7 * EMB + lo);
    ax += __uint_as_float(v0 << 16) + __uint_as_float(v1 << 16) +
          __uint_as_float(v2 << 16) + __uint_as_float(v3 << 16) +
          __uint_as_float(v4 << 16) + __uint_as_float(v5 << 16) +
          __uint_as_float(v6 << 16) + __uint_as_float(v7 << 16);
    ay += __uint_as_float(v0 & 0xffff0000u) + __uint_as_float(v1 & 0xffff0000u) +
          __uint_as_float(v2 & 0xffff0000u) + __uint_as_float(v3 & 0xffff0000u) +
          __uint_as_float(v4 & 0xffff0000u) + __uint_as_float(v5 & 0xffff0000u) +
          __uint_as_float(v6 & 0xffff0000u) + __uint_as_float(v7 & 0xffff0000u);
  }
  for (; i < cnt; ++i) {
    int s = csr[start + i];
    uint32 v = *(const uint32*)(in + (size_t)s * EMB + lo);
    ax += __uint_as_float(v << 16);
    ay += __uint_as_float(v & 0xffff0000u);
  }
  float di = deginv[node];
  uint32 packed = (uint32)f2bf(ax * di) | ((uint32)f2bf(ay * di) << 16);
  *(uint32*)(out + (size_t)node * EMB + lo) = packed;
}

// ---------------- fused MFMA GEMM: out = relu([A|S] @ WcatT + bias), bf16 ----
__global__ __launch_bounds__(256) void k_gemm(const unsigned short* __restrict__ A,
                                              const unsigned short* __restrict__ S,
                                              const unsigned short* __restrict__ Wcat,
                                              const float* __restrict__ bias,
                                              unsigned short* __restrict__ out) {
  int wid = threadIdx.x >> 6;
  int lane = threadIdx.x & 63;
  int rows0 = blockIdx.x * 64 + wid * 16;
  int r = lane & 15;
  int khalf = lane >> 4;
  int arow = rows0 + r;
  if (arow > N_NODES - 1) arow = N_NODES - 1;
  const unsigned short* Abase = A + (size_t)arow * EMB + khalf * 8;
  const unsigned short* Sbase = S + (size_t)arow * EMB + khalf * 8;

  f32x4 acc[8] = {};
#pragma unroll
  for (int kc = 0; kc < 8; ++kc) {
    const unsigned short* p = (kc < 4) ? (Abase + kc * 32) : (Sbase + (kc - 4) * 32);
    bf16x8 a = *(const bf16x8*)p;
#pragma unroll
    for (int jc = 0; jc < 8; ++jc) {
      bf16x8 b = *(const bf16x8*)(Wcat + (size_t)(jc * 16 + r) * 256 + kc * 32 + khalf * 8);
      acc[jc] = __builtin_amdgcn_mfma_f32_16x16x32_bf16(a, b, acc[jc], 0, 0, 0);
    }
  }

  int rbase = (lane >> 4) * 4;
#pragma unroll
  for (int jc = 0; jc < 8; ++jc) {
    int col = jc * 16 + r;
    float bv = bias[col];
#pragma unroll
    for (int q = 0; q < 4; ++q) {
      int row = rows0 + rbase + q;
      if (row < N_NODES) {
        float v = fmaxf(acc[jc][q] + bv, 0.f);
        out[(size_t)row * EMB + col] = f2bf(v);
      }
    }
  }
}

// ---------------- mean pooling per graph + linear head -----------------------
__global__ void k_pool(const unsigned short* __restrict__ h, const int* __restrict__ batch,
                       const float* __restrict__ lw, const float* __restrict__ lb,
                       float* __restrict__ out) {
  int g = blockIdx.x;
  int tid = threadIdx.x;  // 128
  int lo = 0, hi = N_NODES;
  while (lo < hi) {
    int mid = (lo + hi) >> 1;
    if (batch[mid] < g) lo = mid + 1; else hi = mid;
  }
  int lo2 = lo, hi2 = N_NODES;
  while (lo2 < hi2) {
    int mid = (lo2 + hi2) >> 1;
    if (batch[mid] < g + 1) lo2 = mid + 1; else hi2 = mid;
  }
  float sum = 0.f;
  for (int n = lo; n < lo2; ++n) sum += bf2f(h[(size_t)n * EMB + tid]);
  int cnt = lo2 - lo;
  float pooled = sum / fmaxf((float)cnt, 1.0f);
  __shared__ float pl[EMB];
  pl[tid] = pooled;
  __syncthreads();
  if (tid < N_CLASS) {
    float o = lb[tid];
    for (int d = 0; d < EMB; ++d) o += pl[d] * lw[tid * EMB + d];
    out[g * N_CLASS + tid] = o;
  }
}

extern "C" void kernel_launch(void* const* d_in, const int* in_sizes, int n_in,
                              void* d_out, int out_size, void* d_ws, size_t ws_size,
                              hipStream_t stream) {
  const int* nf = (const int*)d_in[0];
  const int* ei = (const int*)d_in[1];
  const int* batch = (const int*)d_in[2];
  const float* se = (const float*)d_in[3];
  const float* ce = (const float*)d_in[4];
  const float* pe = (const float*)d_in[5];
  const float* w1l = (const float*)d_in[6];
  const float* b1l = (const float*)d_in[7];
  const float* w1r = (const float*)d_in[8];
  const float* w2l = (const float*)d_in[9];
  const float* b2l = (const float*)d_in[10];
  const float* w2r = (const float*)d_in[11];
  const float* linw = (const float*)d_in[12];
  const float* linb = (const float*)d_in[13];
  float* out = (float*)d_out;

  char* ws = (char*)d_ws;
  size_t off = 0;
  auto alloc = [&](size_t bytes) {
    void* p = ws + off;
    off = (off + bytes + 255) & ~(size_t)255;
    return p;
  };
  unsigned short* X = (unsigned short*)alloc((size_t)N_NODES * EMB * 2);
  unsigned short* H = (unsigned short*)alloc((size_t)N_NODES * EMB * 2);
  unsigned short* AGG = (unsigned short*)alloc((size_t)N_NODES * EMB * 2);
  unsigned short* WC1 = (unsigned short*)alloc((size_t)256 * EMB * 2);
  unsigned short* WC2 = (unsigned short*)alloc((size_t)256 * EMB * 2);
  float* deginv = (float*)alloc((size_t)N_NODES * 4);
  int* degi = (int*)alloc((size_t)N_NODES * 4);
  int* offs = (int*)alloc((size_t)N_NODES * 4);
  int* part = (int*)alloc((size_t)128 * 4);
  int* rank = (int*)alloc((size_t)N_EDGES * 4);
  int* csr = (int*)alloc((size_t)N_EDGES * 4);

  const int* srcv = ei;
  const int* dstv = ei + N_EDGES;

  hipMemsetAsync(degi, 0, (size_t)N_NODES * 4, stream);
  k_embed<<<(N_NODES * 16 + 255) / 256, 256, 0, stream>>>(nf, se, ce, pe, X);
  k_rank<<<(N_EDGES + 255) / 256, 256, 0, stream>>>(dstv, degi, rank);
  k_scan1<<<NB_SCAN, SCAN_B, 0, stream>>>(degi, offs, part);
  k_scan2<<<1, 128, 0, stream>>>(part);
  k_fin<<<(N_NODES + 255) / 256, 256, 0, stream>>>(offs, part, degi, deginv);
  k_fill<<<(N_EDGES + 255) / 256, 256, 0, stream>>>(srcv, dstv, offs, rank, csr);
  k_wcat<<<128, 256, 0, stream>>>(w1l, w1r, WC1);
  k_wcat<<<128, 256, 0, stream>>>(w2l, w2r, WC2);

  k_agg<<<N_NODES / 4, 256, 0, stream>>>(X, AGG, offs, degi, deginv, csr);
  k_gemm<<<(N_NODES + 63) / 64, 256, 0, stream>>>(AGG, X, WC1, b1l, H);
  k_agg<<<N_NODES / 4, 256, 0, stream>>>(H, AGG, offs, degi, deginv, csr);
  k_gemm<<<(N_NODES + 63) / 64, 256, 0, stream>>>(AGG, H, WC2, b2l, X);
  k_pool<<<N_GRAPH, EMB, 0, stream>>>(X, batch, linw, linb, out);
}